// Round 1
// 745.676 us; speedup vs baseline: 1.0546x; 1.0546x over previous
//
#include <hip/hip_runtime.h>

#define BB 128       // batch
#define DD 128       // feature dim
#define KK1 2048     // K+1
#define NROWS 200000 // memory bank rows

static constexpr float INV_T = 1.0f / 0.07f;
static constexpr float MOM = 0.5f;

typedef float f4 __attribute__((ext_vector_type(4)));

// ---------------------------------------------------------------------------
// Fused kernel: block-role interleave.
//   Every 5th block (r==2) is a COPY block: grid-stride float4 copy of the
//   4 memory banks with non-temporal stores (write data is never re-read;
//   keep L2/L3 free for the gather's source lines).
//   Other blocks are OUTS blocks: 2 (b,k) pairs per wave, half-wave per row,
//   float4 loads (16B/lane), 5-round shfl_xor reduce within each 32-lane half.
// ---------------------------------------------------------------------------
#define COPY_BLOCKS 8192
#define OUTS_BLOCKS 32768
#define TOTAL_BLOCKS (COPY_BLOCKS * 5) // 40960 = 8192 copy + 32768 outs

__global__ __launch_bounds__(256) void fused_kernel(
    const float* __restrict__ l, const float* __restrict__ ab,
    const float* __restrict__ ori, const float* __restrict__ comp,
    const int* __restrict__ idx,
    const float* __restrict__ ml, const float* __restrict__ mab,
    const float* __restrict__ mori, const float* __restrict__ mcomp,
    float* __restrict__ outs,
    float* __restrict__ ol, float* __restrict__ oab,
    float* __restrict__ oori, float* __restrict__ ocomp) {
  const int bid = blockIdx.x;
  const int q = bid / 5;
  const int r = bid - q * 5;

  if (r == 2) {
    // ---- COPY role: cb = q in [0, COPY_BLOCKS) ----
    const int n = NROWS * DD / 4; // 6,400,000 float4 per bank
    const int stride = COPY_BLOCKS * 256;
    const f4* s0 = (const f4*)ml;
    const f4* s1 = (const f4*)mab;
    const f4* s2 = (const f4*)mori;
    const f4* s3 = (const f4*)mcomp;
    f4* d0 = (f4*)ol;
    f4* d1 = (f4*)oab;
    f4* d2 = (f4*)oori;
    f4* d3 = (f4*)ocomp;
    for (int i = q * 256 + threadIdx.x; i < n; i += stride) {
      f4 a0 = s0[i];
      f4 a1 = s1[i];
      f4 a2 = s2[i];
      f4 a3 = s3[i];
      __builtin_nontemporal_store(a0, d0 + i);
      __builtin_nontemporal_store(a1, d1 + i);
      __builtin_nontemporal_store(a2, d2 + i);
      __builtin_nontemporal_store(a3, d3 + i);
    }
    return;
  }

  // ---- OUTS role: ob in [0, OUTS_BLOCKS) ----
  const int ob = bid - q - (r > 2 ? 1 : 0);
  const int lane = threadIdx.x & 63;
  const int hl = lane & 31;                       // lane within half-wave
  const int w = ob * 8 + ((threadIdx.x >> 6) << 1) + (lane >> 5); // (b,k) id
  const int b = w >> 11;                          // K1 = 2048

  const int row = idx[w];
  const size_t roff = (size_t)row * DD;

  const f4 wl    = ((const f4*)(ml    + roff))[hl];
  const f4 wab   = ((const f4*)(mab   + roff))[hl];
  const f4 wori  = ((const f4*)(mori  + roff))[hl];
  const f4 wcomp = ((const f4*)(mcomp + roff))[hl];

  const size_t voff = (size_t)b * DD;
  const f4 vl    = ((const f4*)(l    + voff))[hl];
  const f4 vab   = ((const f4*)(ab   + voff))[hl];
  const f4 vori  = ((const f4*)(ori  + voff))[hl];
  const f4 vcomp = ((const f4*)(comp + voff))[hl];

  // stack order: [l_ori, ab_l, ori_ab, ab_comp, l_comp, comp_ori]
  float d0 = wori[0]*vl[0]    + wori[1]*vl[1]    + wori[2]*vl[2]    + wori[3]*vl[3];
  float d1 = wl[0]*vab[0]     + wl[1]*vab[1]     + wl[2]*vab[2]     + wl[3]*vab[3];
  float d2 = wab[0]*vori[0]   + wab[1]*vori[1]   + wab[2]*vori[2]   + wab[3]*vori[3];
  float d3 = wcomp[0]*vab[0]  + wcomp[1]*vab[1]  + wcomp[2]*vab[2]  + wcomp[3]*vab[3];
  float d4 = wcomp[0]*vl[0]   + wcomp[1]*vl[1]   + wcomp[2]*vl[2]   + wcomp[3]*vl[3];
  float d5 = wori[0]*vcomp[0] + wori[1]*vcomp[1] + wori[2]*vcomp[2] + wori[3]*vcomp[3];

  // reduce within each 32-lane half (xor masks < 32 never cross the boundary)
#pragma unroll
  for (int m = 16; m > 0; m >>= 1) {
    d0 += __shfl_xor(d0, m);
    d1 += __shfl_xor(d1, m);
    d2 += __shfl_xor(d2, m);
    d3 += __shfl_xor(d3, m);
    d4 += __shfl_xor(d4, m);
    d5 += __shfl_xor(d5, m);
  }

  if (hl == 0) {
    const int BK = BB * KK1;
    outs[0 * BK + w] = d0 * INV_T;
    outs[1 * BK + w] = d1 * INV_T;
    outs[2 * BK + w] = d2 * INV_T;
    outs[3 * BK + w] = d3 * INV_T;
    outs[4 * BK + w] = d4 * INV_T;
    outs[5 * BK + w] = d5 * INV_T;
  }
}

// ---------------------------------------------------------------------------
// EMA update + L2 normalize for rows y. grid = (B, 4 banks), 64 threads.
// Runs after the fused kernel (stream-ordered), so its row writes override
// the copied rows: last-write-wins on duplicate y.
// ---------------------------------------------------------------------------
__global__ __launch_bounds__(64) void ema_kernel(
    const float* __restrict__ l, const float* __restrict__ ab,
    const float* __restrict__ ori, const float* __restrict__ comp,
    const int* __restrict__ y,
    const float* __restrict__ ml, const float* __restrict__ mab,
    const float* __restrict__ mori, const float* __restrict__ mcomp,
    float* __restrict__ ol, float* __restrict__ oab,
    float* __restrict__ oori, float* __restrict__ ocomp) {
  const int b = blockIdx.x;
  const int bank = blockIdx.y;
  const int row = y[b];
  // last-write-wins: if a later b' targets the same row, this block bows out
  for (int b2 = b + 1; b2 < BB; ++b2)
    if (y[b2] == row) return;

  const float* v;
  const float* mem;
  float* out;
  switch (bank) {
    case 0: v = l;    mem = ml;    out = ol;    break;
    case 1: v = ab;   mem = mab;   out = oab;   break;
    case 2: v = ori;  mem = mori;  out = oori;  break;
    default: v = comp; mem = mcomp; out = ocomp; break;
  }

  const int lane = threadIdx.x;
  const float2 m2 = ((const float2*)(mem + (size_t)row * DD))[lane];
  const float2 v2 = ((const float2*)(v + (size_t)b * DD))[lane];
  float2 p;
  p.x = m2.x * MOM + v2.x * (1.0f - MOM);
  p.y = m2.y * MOM + v2.y * (1.0f - MOM);

  float ss = p.x * p.x + p.y * p.y;
#pragma unroll
  for (int off = 32; off > 0; off >>= 1) ss += __shfl_down(ss, off);
  ss = __shfl(ss, 0);
  const float inv = 1.0f / sqrtf(ss);

  ((float2*)(out + (size_t)row * DD))[lane] = make_float2(p.x * inv, p.y * inv);
}

extern "C" void kernel_launch(void* const* d_in, const int* in_sizes, int n_in,
                              void* d_out, int out_size, void* d_ws, size_t ws_size,
                              hipStream_t stream) {
  const float* l     = (const float*)d_in[0];
  const float* ab    = (const float*)d_in[1];
  const float* ori   = (const float*)d_in[2];
  const float* comp  = (const float*)d_in[3];
  const int*   y     = (const int*)d_in[4];
  const int*   idx   = (const int*)d_in[5];
  const float* ml    = (const float*)d_in[6];
  const float* mab   = (const float*)d_in[7];
  const float* mori  = (const float*)d_in[8];
  const float* mcomp = (const float*)d_in[9];

  float* out = (float*)d_out;
  const size_t OUTS = (size_t)6 * BB * KK1;          // 1,572,864
  const size_t BANK = (size_t)NROWS * DD;            // 25,600,000
  float* o_outs  = out;
  float* o_ml    = out + OUTS;
  float* o_mab   = o_ml + BANK;
  float* o_mori  = o_mab + BANK;
  float* o_mcomp = o_mori + BANK;

  // 1) fused outs + bank copy (interleaved block roles)
  fused_kernel<<<TOTAL_BLOCKS, 256, 0, stream>>>(
      l, ab, ori, comp, idx, ml, mab, mori, mcomp,
      o_outs, o_ml, o_mab, o_mori, o_mcomp);

  // 2) EMA rows (after copy; stream-ordered)
  {
    dim3 grid(BB, 4);
    ema_kernel<<<grid, 64, 0, stream>>>(l, ab, ori, comp, y,
                                        ml, mab, mori, mcomp,
                                        o_ml, o_mab, o_mori, o_mcomp);
  }
}

// Round 2
// 707.132 us; speedup vs baseline: 1.1121x; 1.0545x over previous
//
#include <hip/hip_runtime.h>

#define BB 128       // batch
#define DD 128       // feature dim
#define KK1 2048     // K+1
#define NROWS 200000 // memory bank rows
#define NPAIR (BB * KK1) // 262144 (b,k) pairs
#define SLOTS 16     // bucket capacity per row (lambda=1.31, P(overflow)~2e-7)

static constexpr float INV_T = 1.0f / 0.07f;
static constexpr float MOM = 0.5f;

typedef float f4 __attribute__((ext_vector_type(4)));

// ---------------------------------------------------------------------------
// Inverted-index build: for each row r of the banks, which pairs p reference
// it (idx[p] == r). counts + fixed-capacity buckets in workspace.
// ---------------------------------------------------------------------------
__global__ __launch_bounds__(256) void zero_cnt_kernel(int* __restrict__ cnt) {
  const int i = blockIdx.x * 256 + threadIdx.x;
  if (i < NROWS) cnt[i] = 0;
}

__global__ __launch_bounds__(256) void build_kernel(const int* __restrict__ idx,
                                                    int* __restrict__ cnt,
                                                    int* __restrict__ bucket) {
  const int p = blockIdx.x * 256 + threadIdx.x; // NPAIR/256 = 1024 blocks, exact
  const int r = idx[p];
  const int s = atomicAdd(&cnt[r], 1);
  if (s < SLOTS) bucket[r * SLOTS + s] = p;
}

// ---------------------------------------------------------------------------
// Streaming copy of the 4 banks + in-register dot products.
// Half-wave (32 lanes x float4) holds one full 128-float row of each bank.
// The row data loaded for the copy IS the gather operand: zero gather traffic.
// NT loads/stores keep L2/L3 clean (nothing here is re-read).
// Per row: for each pair p in its bucket, 6 dots vs the (tiny, cache-hot)
// batch vectors, 5-round shfl_xor reduce within the half-wave, scatter store.
// ---------------------------------------------------------------------------
__global__ __launch_bounds__(256) void copy_dots_kernel(
    const float* __restrict__ l, const float* __restrict__ ab,
    const float* __restrict__ ori, const float* __restrict__ comp,
    const int* __restrict__ cnt, const int* __restrict__ bucket,
    const float* __restrict__ ml, const float* __restrict__ mab,
    const float* __restrict__ mori, const float* __restrict__ mcomp,
    float* __restrict__ outs,
    float* __restrict__ ol, float* __restrict__ oab,
    float* __restrict__ oori, float* __restrict__ ocomp) {
  const int lane = threadIdx.x & 63;
  const int hl = lane & 31;                 // lane within half-wave
  const int half = lane >> 5;
  const int row = blockIdx.x * 8 + ((threadIdx.x >> 6) << 1) + half; // 25000*8 = 200000, exact
  const size_t roff = (size_t)row * DD;

  const f4 wl    = __builtin_nontemporal_load((const f4*)(ml    + roff) + hl);
  const f4 wab   = __builtin_nontemporal_load((const f4*)(mab   + roff) + hl);
  const f4 wori  = __builtin_nontemporal_load((const f4*)(mori  + roff) + hl);
  const f4 wcomp = __builtin_nontemporal_load((const f4*)(mcomp + roff) + hl);

  __builtin_nontemporal_store(wl,    (f4*)(ol    + roff) + hl);
  __builtin_nontemporal_store(wab,   (f4*)(oab   + roff) + hl);
  __builtin_nontemporal_store(wori,  (f4*)(oori  + roff) + hl);
  __builtin_nontemporal_store(wcomp, (f4*)(ocomp + roff) + hl);

  int c = cnt[row];
  if (c > SLOTS) c = SLOTS;
  for (int s = 0; s < c; ++s) {
    const int p = bucket[row * SLOTS + s];
    const int b = p >> 11; // K1 = 2048
    const size_t voff = (size_t)b * DD;
    const f4 vl    = ((const f4*)(l    + voff))[hl];
    const f4 vab   = ((const f4*)(ab   + voff))[hl];
    const f4 vori  = ((const f4*)(ori  + voff))[hl];
    const f4 vcomp = ((const f4*)(comp + voff))[hl];

    // stack order: [l_ori, ab_l, ori_ab, ab_comp, l_comp, comp_ori]
    float d0 = wori[0]*vl[0]    + wori[1]*vl[1]    + wori[2]*vl[2]    + wori[3]*vl[3];
    float d1 = wl[0]*vab[0]     + wl[1]*vab[1]     + wl[2]*vab[2]     + wl[3]*vab[3];
    float d2 = wab[0]*vori[0]   + wab[1]*vori[1]   + wab[2]*vori[2]   + wab[3]*vori[3];
    float d3 = wcomp[0]*vab[0]  + wcomp[1]*vab[1]  + wcomp[2]*vab[2]  + wcomp[3]*vab[3];
    float d4 = wcomp[0]*vl[0]   + wcomp[1]*vl[1]   + wcomp[2]*vl[2]   + wcomp[3]*vl[3];
    float d5 = wori[0]*vcomp[0] + wori[1]*vcomp[1] + wori[2]*vcomp[2] + wori[3]*vcomp[3];

    // reduce within the 32-lane half (xor masks < 32 never cross the boundary;
    // safe under half-divergent loop counts: sources stay within the active half)
#pragma unroll
    for (int m = 16; m > 0; m >>= 1) {
      d0 += __shfl_xor(d0, m);
      d1 += __shfl_xor(d1, m);
      d2 += __shfl_xor(d2, m);
      d3 += __shfl_xor(d3, m);
      d4 += __shfl_xor(d4, m);
      d5 += __shfl_xor(d5, m);
    }

    if (hl == 0) {
      outs[0 * NPAIR + p] = d0 * INV_T;
      outs[1 * NPAIR + p] = d1 * INV_T;
      outs[2 * NPAIR + p] = d2 * INV_T;
      outs[3 * NPAIR + p] = d3 * INV_T;
      outs[4 * NPAIR + p] = d4 * INV_T;
      outs[5 * NPAIR + p] = d5 * INV_T;
    }
  }
}

// ---------------------------------------------------------------------------
// FALLBACK (ws too small): round-1 fused block-role kernel.
// ---------------------------------------------------------------------------
#define COPY_BLOCKS 8192
#define TOTAL_BLOCKS (COPY_BLOCKS * 5)

__global__ __launch_bounds__(256) void fused_kernel(
    const float* __restrict__ l, const float* __restrict__ ab,
    const float* __restrict__ ori, const float* __restrict__ comp,
    const int* __restrict__ idx,
    const float* __restrict__ ml, const float* __restrict__ mab,
    const float* __restrict__ mori, const float* __restrict__ mcomp,
    float* __restrict__ outs,
    float* __restrict__ ol, float* __restrict__ oab,
    float* __restrict__ oori, float* __restrict__ ocomp) {
  const int bid = blockIdx.x;
  const int q = bid / 5;
  const int r = bid - q * 5;

  if (r == 2) {
    const int n = NROWS * DD / 4;
    const int stride = COPY_BLOCKS * 256;
    const f4* s0 = (const f4*)ml;
    const f4* s1 = (const f4*)mab;
    const f4* s2 = (const f4*)mori;
    const f4* s3 = (const f4*)mcomp;
    f4* d0 = (f4*)ol;
    f4* d1 = (f4*)oab;
    f4* d2 = (f4*)oori;
    f4* d3 = (f4*)ocomp;
    for (int i = q * 256 + threadIdx.x; i < n; i += stride) {
      f4 a0 = s0[i];
      f4 a1 = s1[i];
      f4 a2 = s2[i];
      f4 a3 = s3[i];
      __builtin_nontemporal_store(a0, d0 + i);
      __builtin_nontemporal_store(a1, d1 + i);
      __builtin_nontemporal_store(a2, d2 + i);
      __builtin_nontemporal_store(a3, d3 + i);
    }
    return;
  }

  const int ob = bid - q - (r > 2 ? 1 : 0);
  const int lane = threadIdx.x & 63;
  const int hl = lane & 31;
  const int w = ob * 8 + ((threadIdx.x >> 6) << 1) + (lane >> 5);
  const int b = w >> 11;

  const int row = idx[w];
  const size_t roff = (size_t)row * DD;

  const f4 wl    = ((const f4*)(ml    + roff))[hl];
  const f4 wab   = ((const f4*)(mab   + roff))[hl];
  const f4 wori  = ((const f4*)(mori  + roff))[hl];
  const f4 wcomp = ((const f4*)(mcomp + roff))[hl];

  const size_t voff = (size_t)b * DD;
  const f4 vl    = ((const f4*)(l    + voff))[hl];
  const f4 vab   = ((const f4*)(ab   + voff))[hl];
  const f4 vori  = ((const f4*)(ori  + voff))[hl];
  const f4 vcomp = ((const f4*)(comp + voff))[hl];

  float d0 = wori[0]*vl[0]    + wori[1]*vl[1]    + wori[2]*vl[2]    + wori[3]*vl[3];
  float d1 = wl[0]*vab[0]     + wl[1]*vab[1]     + wl[2]*vab[2]     + wl[3]*vab[3];
  float d2 = wab[0]*vori[0]   + wab[1]*vori[1]   + wab[2]*vori[2]   + wab[3]*vori[3];
  float d3 = wcomp[0]*vab[0]  + wcomp[1]*vab[1]  + wcomp[2]*vab[2]  + wcomp[3]*vab[3];
  float d4 = wcomp[0]*vl[0]   + wcomp[1]*vl[1]   + wcomp[2]*vl[2]   + wcomp[3]*vl[3];
  float d5 = wori[0]*vcomp[0] + wori[1]*vcomp[1] + wori[2]*vcomp[2] + wori[3]*vcomp[3];

#pragma unroll
  for (int m = 16; m > 0; m >>= 1) {
    d0 += __shfl_xor(d0, m);
    d1 += __shfl_xor(d1, m);
    d2 += __shfl_xor(d2, m);
    d3 += __shfl_xor(d3, m);
    d4 += __shfl_xor(d4, m);
    d5 += __shfl_xor(d5, m);
  }

  if (hl == 0) {
    outs[0 * NPAIR + w] = d0 * INV_T;
    outs[1 * NPAIR + w] = d1 * INV_T;
    outs[2 * NPAIR + w] = d2 * INV_T;
    outs[3 * NPAIR + w] = d3 * INV_T;
    outs[4 * NPAIR + w] = d4 * INV_T;
    outs[5 * NPAIR + w] = d5 * INV_T;
  }
}

// ---------------------------------------------------------------------------
// EMA update + L2 normalize for rows y. grid = (B, 4 banks), 64 threads.
// Runs after the copy (stream-ordered): overwrites copied rows.
// ---------------------------------------------------------------------------
__global__ __launch_bounds__(64) void ema_kernel(
    const float* __restrict__ l, const float* __restrict__ ab,
    const float* __restrict__ ori, const float* __restrict__ comp,
    const int* __restrict__ y,
    const float* __restrict__ ml, const float* __restrict__ mab,
    const float* __restrict__ mori, const float* __restrict__ mcomp,
    float* __restrict__ ol, float* __restrict__ oab,
    float* __restrict__ oori, float* __restrict__ ocomp) {
  const int b = blockIdx.x;
  const int bank = blockIdx.y;
  const int row = y[b];
  for (int b2 = b + 1; b2 < BB; ++b2)
    if (y[b2] == row) return; // last-write-wins

  const float* v;
  const float* mem;
  float* out;
  switch (bank) {
    case 0: v = l;    mem = ml;    out = ol;    break;
    case 1: v = ab;   mem = mab;   out = oab;   break;
    case 2: v = ori;  mem = mori;  out = oori;  break;
    default: v = comp; mem = mcomp; out = ocomp; break;
  }

  const int lane = threadIdx.x;
  const float2 m2 = ((const float2*)(mem + (size_t)row * DD))[lane];
  const float2 v2 = ((const float2*)(v + (size_t)b * DD))[lane];
  float2 p;
  p.x = m2.x * MOM + v2.x * (1.0f - MOM);
  p.y = m2.y * MOM + v2.y * (1.0f - MOM);

  float ss = p.x * p.x + p.y * p.y;
#pragma unroll
  for (int off = 32; off > 0; off >>= 1) ss += __shfl_down(ss, off);
  ss = __shfl(ss, 0);
  const float inv = 1.0f / sqrtf(ss);

  ((float2*)(out + (size_t)row * DD))[lane] = make_float2(p.x * inv, p.y * inv);
}

extern "C" void kernel_launch(void* const* d_in, const int* in_sizes, int n_in,
                              void* d_out, int out_size, void* d_ws, size_t ws_size,
                              hipStream_t stream) {
  const float* l     = (const float*)d_in[0];
  const float* ab    = (const float*)d_in[1];
  const float* ori   = (const float*)d_in[2];
  const float* comp  = (const float*)d_in[3];
  const int*   y     = (const int*)d_in[4];
  const int*   idx   = (const int*)d_in[5];
  const float* ml    = (const float*)d_in[6];
  const float* mab   = (const float*)d_in[7];
  const float* mori  = (const float*)d_in[8];
  const float* mcomp = (const float*)d_in[9];

  float* out = (float*)d_out;
  const size_t OUTS = (size_t)6 * NPAIR;   // 1,572,864
  const size_t BANK = (size_t)NROWS * DD;  // 25,600,000
  float* o_outs  = out;
  float* o_ml    = out + OUTS;
  float* o_mab   = o_ml + BANK;
  float* o_mori  = o_mab + BANK;
  float* o_mcomp = o_mori + BANK;

  const size_t WS_NEEDED = (size_t)NROWS * SLOTS * sizeof(int) + (size_t)NROWS * sizeof(int);

  if (ws_size >= WS_NEEDED) {
    int* bucket = (int*)d_ws;                 // [NROWS][SLOTS]
    int* cnt    = bucket + (size_t)NROWS * SLOTS;

    zero_cnt_kernel<<<(NROWS + 255) / 256, 256, 0, stream>>>(cnt);
    build_kernel<<<NPAIR / 256, 256, 0, stream>>>(idx, cnt, bucket);
    copy_dots_kernel<<<NROWS / 8, 256, 0, stream>>>(
        l, ab, ori, comp, cnt, bucket, ml, mab, mori, mcomp,
        o_outs, o_ml, o_mab, o_mori, o_mcomp);
  } else {
    fused_kernel<<<TOTAL_BLOCKS, 256, 0, stream>>>(
        l, ab, ori, comp, idx, ml, mab, mori, mcomp,
        o_outs, o_ml, o_mab, o_mori, o_mcomp);
  }

  {
    dim3 grid(BB, 4);
    ema_kernel<<<grid, 64, 0, stream>>>(l, ab, ori, comp, y,
                                        ml, mab, mori, mcomp,
                                        o_ml, o_mab, o_mori, o_mcomp);
  }
}